// Round 9
// baseline (158.720 us; speedup 1.0000x reference)
//
#include <hip/hip_runtime.h>
#include <hip/hip_bf16.h>
#include <stdint.h>

#define T_DIM 4096
#define H_DIM 1024
#define I_DIM 2048

typedef __bf16 bf16x8 __attribute__((ext_vector_type(8)));
typedef float f32x4 __attribute__((ext_vector_type(4)));
typedef unsigned short ushort_t;
typedef unsigned short us4 __attribute__((ext_vector_type(4)));

__device__ __forceinline__ unsigned short f32_to_bf16(float f) {
  unsigned int u = __float_as_uint(f);
  u += 0x7fffu + ((u >> 16) & 1u);  // RNE
  return (unsigned short)(u >> 16);
}

__device__ __forceinline__ void gload_lds16(const void* g, void* l) {
  __builtin_amdgcn_global_load_lds(
      (__attribute__((address_space(1))) void*)(uintptr_t)g,
      (__attribute__((address_space(3))) void*)(unsigned int)(uintptr_t)l,
      16, 0, 0);
}

// XOR swizzle (involution, bits 4-6 ^= bits 7-9). Verified R4: conflicts -> 0.
// Transparent to +1024*n adds (no carries into bits 7-9).
__device__ __forceinline__ int swz(int L) { return L ^ (((L >> 7) & 7) << 4); }

#define S_BARRIER() asm volatile("s_barrier" ::: "memory")
#define WAITV(n) asm volatile("s_waitcnt vmcnt(" #n ")" ::: "memory")
#define LGKM0() asm volatile("s_waitcnt lgkmcnt(0)" ::: "memory")
#define LGKM8() asm volatile("s_waitcnt lgkmcnt(8)" ::: "memory")
#define SCHEDB() __builtin_amdgcn_sched_barrier(0)
#define IRFENCE() asm volatile("" ::: "memory")
#define MFMA16(acc, va, vb) \
  acc = __builtin_amdgcn_mfma_f32_16x16x32_bf16(va, vb, acc, 0, 0, 0)

// ------- rmsnorm + out-init fused ---------------------------------------------
__global__ __launch_bounds__(256) void k_rmsnorm_init(
    const float* __restrict__ x, const float* __restrict__ scale,
    const float* __restrict__ b2, ushort_t* __restrict__ normed,
    float* __restrict__ out) {
  const int row = blockIdx.x, tid = threadIdx.x;
  const float4 v = ((const float4*)(x + (size_t)row * H_DIM))[tid];
  float ss = v.x * v.x + v.y * v.y + v.z * v.z + v.w * v.w;
#pragma unroll
  for (int off = 32; off > 0; off >>= 1) ss += __shfl_xor(ss, off);
  __shared__ float wsum[4];
  if ((tid & 63) == 0) wsum[tid >> 6] = ss;
  __syncthreads();
  const float tot = wsum[0] + wsum[1] + wsum[2] + wsum[3];
  const float inv = rsqrtf(tot * (1.0f / H_DIM) + 1e-5f);
  const float4 sc = ((const float4*)scale)[tid];
  us4 o;
  o.x = f32_to_bf16(v.x * inv * sc.x);
  o.y = f32_to_bf16(v.y * inv * sc.y);
  o.z = f32_to_bf16(v.z * inv * sc.z);
  o.w = f32_to_bf16(v.w * inv * sc.w);
  ((us4*)(normed + (size_t)row * H_DIM))[tid] = o;
  const float4 b0 = ((const float4*)b2)[tid];
  const float4 b1 = ((const float4*)(b2 + H_DIM))[tid];
  float4 ov;
  ov.x = v.x + 0.5f * (b0.x + b1.x);
  ov.y = v.y + 0.5f * (b0.y + b1.y);
  ov.z = v.z + 0.5f * (b0.z + b1.z);
  ov.w = v.w + 0.5f * (b0.w + b1.w);
  ((float4*)(out + (size_t)row * H_DIM))[tid] = ov;
}

// ------- transpose+convert: src[R][C] f32 -> dst[C][R] bf16 (per blockIdx.z) ---
__global__ __launch_bounds__(256) void k_transpose_cvt(const float* __restrict__ src,
                                                       ushort_t* __restrict__ dst,
                                                       int R, int C) {
  __shared__ float tile[32][33];
  const size_t eoff = (size_t)blockIdx.z * (size_t)R * (size_t)C;
  src += eoff;
  dst += eoff;
  const int x0 = blockIdx.x * 32, y0 = blockIdx.y * 32;
  const int tx = threadIdx.x & 31, ty = threadIdx.x >> 5;
#pragma unroll
  for (int i = 0; i < 4; ++i)
    tile[ty + 8 * i][tx] = src[(size_t)(y0 + ty + 8 * i) * C + x0 + tx];
  __syncthreads();
#pragma unroll
  for (int i = 0; i < 4; ++i)
    dst[(size_t)(x0 + ty + 8 * i) * R + y0 + tx] = f32_to_bf16(tile[tx][ty + 8 * i]);
}

// ---------------- GEMM1 v5: K-tile register residency + front-loaded staging ---
// 256 rows x (128g+128l), 8 waves 2(wm)x4(wn); per-wave 128 rows x (32g+32l).
// Per K-tile (BK=64): PH1 reads a_ks0[8]+b_ks0[4] (12) & stages U0',U1';
// PH2 reads b_ks1[4] & stages U2',U3'; PH3 reads a_ks1[8]; PH4 pure MFMA.
// Each phase: BAR; lgkm0; 16 MFMA; BAR. WAITV(4) only at PH1-end & PH4-end
// (loads waited on have >=3 phases of slack; never 0 in loop). LDS 128 KiB:
// per buf U0=A_ks0@0, U1=B_ks0@16K, U2=A_ks1@32K, U3=B_ks1@48K.
__global__ __launch_bounds__(512, 2) void k_gemm1(
    const ushort_t* __restrict__ normed, const ushort_t* __restrict__ w1T,
    const float* __restrict__ b1, ushort_t* __restrict__ act) {
  __shared__ __align__(16) ushort_t lds[2][4][8192];  // 128 KiB
  char* const ldsB = (char*)&lds[0][0][0];
  const int tid = threadIdx.x;
  const int wg = (blockIdx.x & 7) * 64 + (blockIdx.x >> 3);  // XCD swizzle
  const int e = wg >> 8;
  const int rem = wg & 255;
  const int brow = (rem >> 4) * 256;
  const int bcol = (rem & 15) * 128;
  const int lane = tid & 63;
  const int wid = tid >> 6;
  const int wm = wid >> 2;   // 0..1 -> 128 rows
  const int wn = wid & 3;    // 0..3 -> 32 gate + 32 linear cols
  const int r16 = lane & 15, kh = lane >> 4;

  const ushort_t* gBase = w1T + ((size_t)e * 2 * I_DIM + bcol) * H_DIM;
  const ushort_t* lBase = gBase + (size_t)I_DIM * H_DIM;

  f32x4 accg[8][2], accl[8][2];
  const f32x4 zf = {0.f, 0.f, 0.f, 0.f};
#pragma unroll
  for (int m = 0; m < 8; ++m)
#pragma unroll
    for (int n = 0; n < 2; ++n) { accg[m][n] = zf; accl[m][n] = zf; }

  // Staging decomposition (pre-swizzled source, linear LDS dest — rule 21).
  int srow[2], scolb[2];
#pragma unroll
  for (int j = 0; j < 2; ++j) {
    const int u = swz((j * 512 + tid) * 16);
    srow[j] = u >> 6;
    scolb[j] = (u & 63) >> 1;
  }
  const int ldst0 = (tid & ~63) * 16;

  const ushort_t* pA0 = normed + (size_t)(brow + srow[0]) * H_DIM + scolb[0];
  const ushort_t* pA1 = normed + (size_t)(brow + srow[1]) * H_DIM + scolb[1];
  const ushort_t* pG = gBase + (size_t)srow[0] * H_DIM + scolb[0];
  const ushort_t* pL = lBase + (size_t)(srow[1] - 128) * H_DIM + scolb[1];

  // Single-VGPR fragment bases; +1024*frag and +32768*ks fold into imms.
  int abase[2], bbase[2];
  {
    const int ab = wm * 8192 + swz(r16 * 64 + kh * 16);
    const int bb = 16384 + swz((wn * 32 + r16) * 64 + kh * 16);
#pragma unroll
    for (int bq = 0; bq < 2; ++bq) {
      abase[bq] = bq * 65536 + ab;
      bbase[bq] = bq * 65536 + bb;
    }
  }

  auto stageA = [&](int buf, int ks) {
    gload_lds16(pA0 + ks * 32, ldsB + buf * 65536 + ks * 32768 + ldst0);
    gload_lds16(pA1 + ks * 32, ldsB + buf * 65536 + ks * 32768 + 8192 + ldst0);
  };
  auto stageB = [&](int buf, int ks) {
    gload_lds16(pG + ks * 32, ldsB + buf * 65536 + ks * 32768 + 16384 + ldst0);
    gload_lds16(pL + ks * 32, ldsB + buf * 65536 + ks * 32768 + 16384 + 8192 + ldst0);
  };

  bf16x8 a[8], bg0[2], bl0[2], bg1[2], bl1[2];

#define RD_A(C, KS)                                                           \
  _Pragma("unroll") for (int m = 0; m < 8; ++m)                               \
      a[m] = *(const bf16x8*)(ldsB + abase[C] + (KS) * 32768 + m * 1024);
#define RD_B(C, KS, BG, BL)                                                   \
  _Pragma("unroll") for (int n = 0; n < 2; ++n) {                             \
    BG[n] = *(const bf16x8*)(ldsB + bbase[C] + (KS) * 32768 + n * 1024);      \
    BL[n] = *(const bf16x8*)(ldsB + bbase[C] + (KS) * 32768 + 8192 + n * 1024);\
  }
#define MFMA_Q(MQ, BG, BL)                                                    \
  _Pragma("unroll") for (int mm = 0; mm < 4; ++mm)                            \
      _Pragma("unroll") for (int n = 0; n < 2; ++n) {                         \
    MFMA16(accg[(MQ) * 4 + mm][n], a[(MQ) * 4 + mm], BG[n]);                  \
    MFMA16(accl[(MQ) * 4 + mm][n], a[(MQ) * 4 + mm], BL[n]);                  \
  }

#define G1_ADV() \
  { pA0 += 64; pA1 += 64; pG += 64; pL += 64; }

#define G1_TILE(C, N)                                                         \
  { /* PH1: 12 reads, stage U0',U1', MFMA m0-3 ks0 */                         \
    RD_A(C, 0);                                                               \
    RD_B(C, 0, bg0, bl0);                                                     \
    stageA(N, 0);                                                             \
    stageB(N, 0);                                                             \
    LGKM8();                                                                  \
    S_BARRIER();                                                              \
    LGKM0();                                                                  \
    SCHEDB();                                                                 \
    __builtin_amdgcn_s_setprio(1);                                            \
    MFMA_Q(0, bg0, bl0);                                                      \
    __builtin_amdgcn_s_setprio(0);                                            \
    WAITV(4); /* drains prev-PH2-staged U2,U3 of C (needed PH2/PH3) */        \
    S_BARRIER();                                                              \
    SCHEDB();                                                                 \
    /* PH2: 4 reads, stage U2',U3', MFMA m4-7 ks0 */                          \
    RD_B(C, 1, bg1, bl1);                                                     \
    stageA(N, 1);                                                             \
    stageB(N, 1);                                                             \
    S_BARRIER();                                                              \
    LGKM0();                                                                  \
    SCHEDB();                                                                 \
    __builtin_amdgcn_s_setprio(1);                                            \
    MFMA_Q(1, bg0, bl0);                                                      \
    __builtin_amdgcn_s_setprio(0);                                            \
    S_BARRIER();                                                              \
    SCHEDB();                                                                 \
    /* PH3: 8 reads, MFMA m0-3 ks1 */                                         \
    RD_A(C, 1);                                                               \
    S_BARRIER();                                                              \
    LGKM0();                                                                  \
    SCHEDB();                                                                 \
    __builtin_amdgcn_s_setprio(1);                                            \
    MFMA_Q(0, bg1, bl1);                                                      \
    __builtin_amdgcn_s_setprio(0);                                            \
    S_BARRIER();                                                              \
    SCHEDB();                                                                 \
    /* PH4: pure MFMA m4-7 ks1; boundary wait */                              \
    __builtin_amdgcn_s_setprio(1);                                            \
    MFMA_Q(1, bg1, bl1);                                                      \
    __builtin_amdgcn_s_setprio(0);                                            \
    WAITV(4); /* drains PH1-staged U0',U1' of N */                            \
    S_BARRIER();                                                              \
    SCHEDB();                                                                 \
    G1_ADV();                                                                 \
  }

  // Prologue: stage tile 0 units in order U0,U1,U2,U3; advance to tile 1.
  stageA(0, 0); stageB(0, 0); IRFENCE();
  stageA(0, 1); stageB(0, 1);
  G1_ADV();
  WAITV(4);  // U0,U1 landed; U2,U3 in flight (drained by tile0 PH1's WAITV)
  S_BARRIER();

#pragma unroll 1
  for (int it = 0; it < 7; ++it) {  // tiles 0..13
    G1_TILE(0, 1);
    G1_TILE(1, 0);
  }
  G1_TILE(0, 1);  // tile 14, stages tile 15 into buf1

  // Tail: tile 15 in buf1 (U0,U1 drained at boundary; U2,U3 in flight).
  {
    RD_A(1, 0);
    RD_B(1, 0, bg0, bl0);
    MFMA_Q(0, bg0, bl0);
    WAITV(0);
    S_BARRIER();  // all waves' U2,U3 staging drained
    RD_B(1, 1, bg1, bl1);
    MFMA_Q(1, bg0, bl0);
    RD_A(1, 1);
    MFMA_Q(0, bg1, bl1);
    MFMA_Q(1, bg1, bl1);
  }
#undef G1_TILE
#undef G1_ADV
#undef RD_A
#undef RD_B
#undef MFMA_Q

  // Epilogue: bias + clip + sigmoid-gate, store bf16 act.
  const float* b1e = b1 + (size_t)e * 2 * I_DIM;
#pragma unroll
  for (int m = 0; m < 8; ++m)
#pragma unroll
    for (int n = 0; n < 2; ++n) {
      const int gcol = bcol + wn * 32 + n * 16 + r16;
      const float bgb = b1e[gcol];
      const float blb = b1e[I_DIM + gcol];
#pragma unroll
      for (int rr = 0; rr < 4; ++rr) {
        const int grow = brow + wm * 128 + m * 16 + kh * 4 + rr;
        const float hg = accg[m][n][rr] + bgb;
        const float hl = accl[m][n][rr] + blb;
        const float g = fminf(hg, 7.f);
        const float l = fminf(fmaxf(hl, -7.f), 7.f);
        const float s = 1.f / (1.f + __expf(-1.702f * g));
        const float av = g * s * (l + 1.f);
        act[((size_t)e * T_DIM + grow) * I_DIM + gcol] = f32_to_bf16(av);
      }
    }
}

// ---------------- GEMM2: 256x128, split-K=2 (expert), 2 barriers/K-tile -------
// (unchanged from R6 — known-good 38 us baseline for the gemm1 A/B)
__global__ __launch_bounds__(512, 2) void k_gemm2(
    const ushort_t* __restrict__ act, const ushort_t* __restrict__ w2T,
    float* __restrict__ out) {
  __shared__ __align__(16) ushort_t lds[2][2][12288];  // 96 KiB
  char* const ldsB = (char*)&lds[0][0][0];
  const int tid = threadIdx.x;
  const int wg = (blockIdx.x & 7) * 32 + (blockIdx.x >> 3);
  const int e = wg >> 7;
  const int tileid = wg & 127;
  const int brow = (tileid >> 3) * 256;
  const int bcol = (tileid & 7) * 128;
  const int lane = tid & 63;
  const int wm = (tid >> 6) >> 1;
  const int wn = (tid >> 6) & 1;
  const int r16 = lane & 15, kh = lane >> 4;

  const ushort_t* aBase = act + ((size_t)e * T_DIM + brow) * I_DIM;
  const ushort_t* bBase = w2T + ((size_t)e * H_DIM + bcol) * I_DIM;

  f32x4 acc[4][4];
  const f32x4 zf = {0.f, 0.f, 0.f, 0.f};
#pragma unroll
  for (int m = 0; m < 4; ++m)
#pragma unroll
    for (int n = 0; n < 4; ++n) acc[m][n] = zf;

  int srow[2], scolb[2];
#pragma unroll
  for (int j = 0; j < 2; ++j) {
    const int u = swz((j * 512 + tid) * 16);
    srow[j] = u >> 6;
    scolb[j] = (u & 63) >> 1;
  }
  const int ldst0 = (tid & ~63) * 16;

  const ushort_t* pA0 = aBase + (size_t)srow[0] * I_DIM + scolb[0];
  const ushort_t* pA1 = aBase + (size_t)srow[1] * I_DIM + scolb[1];
  const ushort_t* pB = bBase + (size_t)srow[0] * I_DIM + scolb[0];

  int aoffV[2][4], boffV[2][4];
#pragma unroll
  for (int bq = 0; bq < 2; ++bq) {
#pragma unroll
    for (int m = 0; m < 4; ++m)
      aoffV[bq][m] = bq * 49152 + swz((wm * 64 + m * 16 + r16) * 64 + kh * 16);
#pragma unroll
    for (int n = 0; n < 4; ++n)
      boffV[bq][n] = bq * 49152 + 16384 + swz((wn * 64 + n * 16 + r16) * 64 + kh * 16);
  }

  auto stageA = [&](int buf, int ksub) {
    gload_lds16(pA0 + ksub * 32, ldsB + buf * 49152 + ksub * 24576 + ldst0);
    gload_lds16(pA1 + ksub * 32, ldsB + buf * 49152 + ksub * 24576 + 8192 + ldst0);
  };
  auto stageB = [&](int buf, int ksub) {
    gload_lds16(pB + ksub * 32, ldsB + buf * 49152 + ksub * 24576 + 16384 + ldst0);
  };
  auto rdA = [&](int buf, int ksub, int m) -> bf16x8 {
    return *(const bf16x8*)(ldsB + aoffV[buf][m] + ksub * 24576);
  };
  auto rdB = [&](int buf, int ksub, int n) -> bf16x8 {
    return *(const bf16x8*)(ldsB + boffV[buf][n] + ksub * 24576);
  };

#define G2_ADV() \
  { pA0 += 64; pA1 += 64; pB += 64; }

#define G2_HALF(CUR, NXT, KS)                                                 \
  {                                                                           \
    _Pragma("unroll") for (int m = 0; m < 4; ++m) a[m] = rdA(CUR, KS, m);     \
    _Pragma("unroll") for (int n = 0; n < 4; ++n) b[n] = rdB(CUR, KS, n);     \
    stageA(NXT, KS);                                                          \
    stageB(NXT, KS);                                                          \
    __builtin_amdgcn_s_setprio(1);                                            \
    _Pragma("unroll") for (int m = 0; m < 4; ++m)                             \
        _Pragma("unroll") for (int n = 0; n < 4; ++n)                         \
            MFMA16(acc[m][n], a[m], b[n]);                                    \
    __builtin_amdgcn_s_setprio(0);                                            \
    WAITV(3);                                                                 \
    S_BARRIER();                                                              \
  }

#define G2_TILE(CUR, NXT)  \
  { G2_HALF(CUR, NXT, 0); G2_HALF(CUR, NXT, 1); G2_ADV(); }

  // Prologue.
  stageA(0, 0); stageB(0, 0); IRFENCE();
  stageA(0, 1); stageB(0, 1);
  G2_ADV();
  WAITV(3);
  S_BARRIER();

  bf16x8 a[4], b[4];
#pragma unroll 1
  for (int it = 0; it < 15; ++it) {  // tiles 0..29
    G2_TILE(0, 1);
    G2_TILE(1, 0);
  }
  G2_TILE(0, 1);  // tile 30, stages 31 into buf1

  // Tail: tile 31 in buf1.
  {
#pragma unroll
    for (int m = 0; m < 4; ++m) a[m] = rdA(1, 0, m);
#pragma unroll
    for (int n = 0; n < 4; ++n) b[n] = rdB(1, 0, n);
#pragma unroll
    for (int m = 0; m < 4; ++m)
#pragma unroll
      for (int n = 0; n < 4; ++n) MFMA16(acc[m][n], a[m], b[n]);
    WAITV(0);
    S_BARRIER();
#pragma unroll
    for (int m = 0; m < 4; ++m) a[m] = rdA(1, 1, m);
#pragma unroll
    for (int n = 0; n < 4; ++n) b[n] = rdB(1, 1, n);
#pragma unroll
    for (int m = 0; m < 4; ++m)
#pragma unroll
      for (int n = 0; n < 4; ++n) MFMA16(acc[m][n], a[m], b[n]);
  }
#undef G2_HALF
#undef G2_TILE
#undef G2_ADV

  // Epilogue: atomic accumulate 0.5*acc into out (pre-initialized x + bias).
#pragma unroll
  for (int m = 0; m < 4; ++m)
#pragma unroll
    for (int n = 0; n < 4; ++n) {
      const int gcol = bcol + wn * 64 + n * 16 + r16;
#pragma unroll
      for (int rr = 0; rr < 4; ++rr) {
        const int grow = brow + wm * 64 + m * 16 + kh * 4 + rr;
        atomicAdd(&out[(size_t)grow * H_DIM + gcol], 0.5f * acc[m][n][rr]);
      }
    }
}

extern "C" void kernel_launch(void* const* d_in, const int* in_sizes, int n_in,
                              void* d_out, int out_size, void* d_ws, size_t ws_size,
                              hipStream_t stream) {
  const float* x = (const float*)d_in[0];
  const float* scale = (const float*)d_in[1];
  // d_in[2]=gate_kernel, d_in[3]=gate_bias: static routing, logits unused.
  const float* w1 = (const float*)d_in[4];
  const float* b1 = (const float*)d_in[5];
  const float* w2 = (const float*)d_in[6];
  const float* b2 = (const float*)d_in[7];
  float* out = (float*)d_out;

  ushort_t* ws = (ushort_t*)d_ws;
  ushort_t* normed = ws;                                    // [T][H]
  ushort_t* w1T = normed + (size_t)T_DIM * H_DIM;           // [2][2I][H]
  ushort_t* w2T = w1T + (size_t)2 * 2 * I_DIM * H_DIM;      // [2][H][I]
  ushort_t* actb = w2T + (size_t)2 * H_DIM * I_DIM;         // [2][T][I]

  k_rmsnorm_init<<<dim3(T_DIM), 256, 0, stream>>>(x, scale, b2, normed, out);
  k_transpose_cvt<<<dim3(2 * I_DIM / 32, H_DIM / 32, 2), 256, 0, stream>>>(
      w1, w1T, H_DIM, 2 * I_DIM);
  k_transpose_cvt<<<dim3(H_DIM / 32, I_DIM / 32, 2), 256, 0, stream>>>(
      w2, w2T, I_DIM, H_DIM);
  k_gemm1<<<dim3(512), 512, 0, stream>>>(normed, w1T, b1, actb);
  k_gemm2<<<dim3(256), 512, 0, stream>>>(actb, w2T, out);
}